// Round 2
// baseline (2012.116 us; speedup 1.0000x reference)
//
#include <hip/hip_runtime.h>

// FeatureAdaptation (deformable conv): B=2, CHI=CHO=256, H=W=128, K=9.
// ROUND 2 = BISECT PROBE: same transpose/pack/metadata/gather pipeline as R1,
// but the GEMM is a plain VALU dot product (no MFMA, no fragment layouts).
// Pass -> R1 bug was MFMA plumbing. Fail -> bug is in gather/meta/transpose/pack.

#define HH 128
#define WW 128
#define CIN 256
#define COUT 256
#define KK9 9
#define HW (HH * WW)            // 16384
#define KDIM (KK9 * CIN)        // 2304
#define BK 32
#define NT (KDIM / BK)          // 72
#define BM 32
#define XT_PER_B (HW * CIN)     // 4194304 elems per batch

__device__ __forceinline__ ushort f2bf(float f) {
  union { float f; unsigned u; } v; v.f = f;
  unsigned u = v.u;
  u += 0x7FFFu + ((u >> 16) & 1u);   // RNE
  return (ushort)(u >> 16);
}
__device__ __forceinline__ float bf2f(ushort h) {
  union { unsigned u; float f; } v; v.u = ((unsigned)h) << 16; return v.f;
}

// ---------------- x (B,C,H,W) f32  ->  xT (B,H,W,C) bf16 ----------------
__global__ __launch_bounds__(256) void k_transpose(const float* __restrict__ x,
                                                   ushort* __restrict__ xT) {
  __shared__ ushort tile[64][130];
  const int bid = blockIdx.x;       // ((b*4 + cb)*128 + y)
  const int y  = bid & 127;
  const int t  = bid >> 7;
  const int cb = t & 3;             // 64-channel chunk
  const int b  = t >> 2;

  const int xl = threadIdx.x & 127;
  const int ch = threadIdx.x >> 7;  // 0..1
  const float* src = x + (size_t)(b * CIN + cb * 64) * HW + y * WW + xl;
#pragma unroll
  for (int i = 0; i < 32; ++i) {
    int c = ch * 32 + i;
    tile[c][xl] = f2bf(src[(size_t)c * HW]);
  }
  __syncthreads();
  const int c  = threadIdx.x & 63;
  const int xh = threadIdx.x >> 6;  // 0..3
  ushort* dst = xT + (size_t)b * XT_PER_B + (size_t)(y * WW) * CIN + cb * 64 + c;
#pragma unroll
  for (int i = 0; i < 32; ++i) {
    int xx = xh * 32 + i;
    dst[(size_t)xx * CIN] = tile[c][xx];
  }
}

// ---------------- conv_w (O,C,3,3) f32 -> Bm[o][k*256+c] bf16 ----------------
__global__ __launch_bounds__(256) void k_packw(const float* __restrict__ cw,
                                               ushort* __restrict__ Bm) {
  int idx = blockIdx.x * 256 + threadIdx.x;   // < 589824
  int o = idx / KDIM;
  int t = idx - o * KDIM;
  int k = t >> 8;
  int c = t & 255;
  Bm[idx] = f2bf(cw[(o * CIN + c) * KK9 + k]);
}

// ---------------- VALU probe: gather + plain dot product ----------------
// grid 1024 = B * H * (W/32); block 256. Per block: 32 pixels x 256 out-ch.
// thread tid owns output channel o = tid for all 32 pixels.
__global__ __launch_bounds__(256) void k_valu(
    const ushort* __restrict__ xT, const ushort* __restrict__ Bm,
    const float* __restrict__ scale, const float* __restrict__ ctr,
    const float* __restrict__ offw, const float* __restrict__ offb,
    const float* __restrict__ mskw, const float* __restrict__ mskb,
    const float* __restrict__ convb, float* __restrict__ out) {
  __shared__ float  As2[32][33];        // [c_local][pixel]
  __shared__ int4   moff[BM * KK9];     // 4 corner element-offsets
  __shared__ float4 mwt[BM * KK9];      // 4 corner weights (mask+validity folded)

  const int tid = threadIdx.x;
  const int mb  = blockIdx.x;
  const int b   = mb >> 9;
  const int rem = mb & 511;
  const int h   = rem >> 2;
  const int w0  = (rem & 3) << 5;

  // ---- prologue: per (pixel,k) bilinear metadata (identical to R1)
  for (int idx = tid; idx < BM * KK9; idx += 256) {
    int p = idx / 9;
    int k = idx - p * 9;
    int w = w0 + p;
    float sc = scale[b * HW + h * WW + w];
    float ct = ctr[b * HW + h * WW + w];
    float dy = sc * offw[2 * k]     + offb[2 * k];
    float dx = sc * offw[2 * k + 1] + offb[2 * k + 1];
    float mk = 1.0f / (1.0f + __expf(-(ct * mskw[k] + mskb[k])));
    float ys = (float)(h + (k / 3) - 1) + dy;
    float xs = (float)(w + (k % 3) - 1) + dx;
    float y0 = floorf(ys), x0 = floorf(xs);
    float wy1 = ys - y0, wx1 = xs - x0;
    float wy0 = 1.f - wy1, wx0 = 1.f - wx1;
    int offc[4]; float wtc[4];
#pragma unroll
    for (int a = 0; a < 2; ++a)
#pragma unroll
      for (int bb = 0; bb < 2; ++bb) {
        float yc = y0 + (float)a, xc = x0 + (float)bb;
        bool valid = (yc >= 0.f) && (yc <= 127.f) && (xc >= 0.f) && (xc <= 127.f);
        int yi = (int)fminf(fmaxf(yc, 0.f), 127.f);
        int xi = (int)fminf(fmaxf(xc, 0.f), 127.f);
        offc[a * 2 + bb] = (yi * WW + xi) * CIN;
        wtc[a * 2 + bb]  = (a ? wy1 : wy0) * (bb ? wx1 : wx0) * mk * (valid ? 1.f : 0.f);
      }
    moff[idx] = make_int4(offc[0], offc[1], offc[2], offc[3]);
    mwt[idx]  = make_float4(wtc[0], wtc[1], wtc[2], wtc[3]);
  }
  __syncthreads();

  const ushort* xTb = xT + (size_t)b * XT_PER_B;

  float acc[32];
#pragma unroll
  for (int p = 0; p < 32; ++p) acc[p] = 0.f;

  for (int t = 0; t < NT; ++t) {
    const int k  = t >> 3;            // kernel tap
    const int c0 = (t & 7) << 5;      // channel base
    // gather 32 channels x 32 pixels, 4 values per thread (identical math to R1)
#pragma unroll
    for (int q = 0; q < 4; ++q) {
      int lin = q * 256 + tid;        // 0..1023
      int c   = lin >> 5;             // local channel 0..31
      int p   = lin & 31;             // pixel 0..31
      int4   off = moff[p * 9 + k];
      float4 wt  = mwt[p * 9 + k];
      int cc = c0 + c;
      float v = wt.x * bf2f(xTb[off.x + cc])
              + wt.y * bf2f(xTb[off.y + cc])
              + wt.z * bf2f(xTb[off.z + cc])
              + wt.w * bf2f(xTb[off.w + cc]);
      As2[c][p] = v;
    }
    __syncthreads();
    // dot: thread tid = out-channel; As2 reads are wave-uniform (broadcast)
    const ushort* bro = Bm + tid * KDIM + t * 32;
#pragma unroll 1
    for (int c = 0; c < 32; ++c) {
      float wv = bf2f(bro[c]);
#pragma unroll
      for (int p = 0; p < 32; ++p) acc[p] += wv * As2[c][p];
    }
    __syncthreads();
  }

  float cbv = convb[tid];
  float* op = out + (size_t)(b * COUT + tid) * HW + h * WW + w0;
#pragma unroll
  for (int p = 0; p < 32; ++p) op[p] = acc[p] + cbv;
}

extern "C" void kernel_launch(void* const* d_in, const int* in_sizes, int n_in,
                              void* d_out, int out_size, void* d_ws, size_t ws_size,
                              hipStream_t stream) {
  const float* x     = (const float*)d_in[0];
  const float* ctr   = (const float*)d_in[1];
  const float* scale = (const float*)d_in[2];
  const float* offw  = (const float*)d_in[3];
  const float* offb  = (const float*)d_in[4];
  const float* mskw  = (const float*)d_in[5];
  const float* mskb  = (const float*)d_in[6];
  const float* cw    = (const float*)d_in[7];
  const float* cb    = (const float*)d_in[8];
  float* out = (float*)d_out;

  ushort* xT = (ushort*)d_ws;                                     // 16.78 MB
  ushort* Bm = (ushort*)((char*)d_ws + (size_t)2 * XT_PER_B * 2); // +1.18 MB

  k_transpose<<<dim3(1024), dim3(256), 0, stream>>>(x, xT);
  k_packw<<<dim3(2304), dim3(256), 0, stream>>>(cw, Bm);
  k_valu<<<dim3(1024), dim3(256), 0, stream>>>(xT, Bm, scale, ctr, offw, offb,
                                               mskw, mskb, cb, out);
}